// Round 12
// baseline (441.343 us; speedup 1.0000x reference)
//
#include <hip/hip_runtime.h>
#include <hip/hip_cooperative_groups.h>
#include <math.h>

namespace cg = cooperative_groups;

#define C      128
#define CAPLG  12
#define CAP    (1 << CAPLG)      // bucket capacity per class (max count ~2300 << 4096)
#define SPLIT  8                 // partials per class (NBLK = C*SPLIT)
#define NBLK   1024              // cooperative grid: 4 blocks/CU x 256 CU
#define NSCAT  256               // scatter-active blocks
#define SPB    1024              // samples per scatter block
#define PBS    260               // partial stride: sp[128] sln[128] pos pad
#define LN2F   0.69314718056f

__device__ __forceinline__ float fast_rcp(float x) { return __builtin_amdgcn_rcpf(x); }

// ---------------------------------------------------------------------------
// One cooperative kernel, 5 phases separated by grid.sync() — zero launch
// gaps, zero memset launch, zero ticket/threadfence (sync gives visibility).
// Phase S and M bodies are the round-5 champion verbatim (S: 256 blocks of
// 1024 samples; M: SPLIT=8 instead of 16 — same total work).
// ---------------------------------------------------------------------------
__global__ __launch_bounds__(256, 4)
void fused_all(const float* __restrict__ x, const int* __restrict__ tgt,
               int* __restrict__ cursor, int* __restrict__ perm,
               float* __restrict__ partial, float* __restrict__ colpart,
               float* __restrict__ out, int B) {
    cg::grid_group grid = cg::this_grid();
    const int tid = threadIdx.x;
    const int bid = blockIdx.x;

    __shared__ __align__(16) float sP[8][C];   // aliased: S->lcur, E1->spcol/slcol
    __shared__ __align__(16) float sX[8][C];   // aliased: S->sbase
    __shared__ __align__(16) float sL[8][C];
    __shared__ float sSmall[16];               // M->sPos, E1->sposr

    // ---- phase Z: zero cursor (replaces hipMemsetAsync launch) ----
    if (bid == 0 && tid < C) cursor[tid] = 0;
    grid.sync();

    // ---- phase S: bucketed counting-sort scatter (champion, blocks 0..255) ----
    if (bid < NSCAT) {
        int* lcur  = (int*)&sP[0][0];
        int* sbase = (int*)&sX[0][0];
        if (tid < C) lcur[tid] = 0;
        __syncthreads();
        const int base = bid * SPB;
        int myt[4], myr[4];
#pragma unroll
        for (int j = 0; j < 4; ++j) {
            int i = base + j * 256 + tid;
            if (i < B) { myt[j] = tgt[i]; myr[j] = atomicAdd(&lcur[myt[j]], 1); }
            else myt[j] = -1;
        }
        __syncthreads();
        if (tid < C) sbase[tid] = atomicAdd(&cursor[tid], lcur[tid]);
        __syncthreads();
#pragma unroll
        for (int j = 0; j < 4; ++j)
            if (myt[j] >= 0)
                perm[(myt[j] << CAPLG) + sbase[myt[j]] + myr[j]] = base + j * 256 + tid;
    }
    grid.sync();

    // ---- phase M: champion main (transcendental roofline ~21 us), SPLIT=8 ----
    {
        const int k = bid >> 3;
        const int p = bid & 7;
        const int n = min(cursor[k], CAP);
        const int chunk = (n + SPLIT - 1) / SPLIT;
        const int s0 = min(p * chunk, n);
        const int s1 = min(s0 + chunk, n);

        const int wave = tid >> 6;
        const int lane = tid & 63;
        const int half = lane >> 5;          // 0 => row A, 1 => row B
        const int l5   = lane & 31;
        const int c0   = l5 << 2;            // this lane's first of 4 columns
        const bool poslane = (l5 == (k >> 2));
        const int  ksub = k & 3;

        const int wlen = (s1 - s0 + 3) >> 2; // per-wave contiguous sub-range
        const int ws0  = s0 + wave * wlen;
        const int ws1  = min(ws0 + wlen, s1);

        const int* bperm = perm + (k << CAPLG);

        float ap0=0,ap1=0,ap2=0,ap3=0;       // sum p
        float sx0=0,sx1=0,sx2=0,sx3=0;       // sum x
        float sl0=0,sl1=0,sl2=0,sl3=0;       // sum log2(1+exp(-x))
        float apos = 0.f;

        for (int tbase = ws0; tbase < ws1; tbase += 64) {
            const int tl = min(64, ws1 - tbase);
            const int pv = (lane < tl) ? bperm[tbase + lane] : 0;
            const int h  = (tl + 1) >> 1;
            int iA = __shfl(pv, 0);
            int iB = __shfl(pv, (h < tl) ? h : 0);
            float4 cur = *reinterpret_cast<const float4*>(
                             x + (size_t)(half ? iB : iA) * C + c0);
            for (int j = 0; j < h; ++j) {
                float4 nxt = cur;
                if (j + 1 < h) {   // prefetch next pair while computing current
                    int nA = __shfl(pv, j + 1);
                    int nB = __shfl(pv, (j + 1 + h < tl) ? j + 1 + h : j + 1);
                    nxt = *reinterpret_cast<const float4*>(
                              x + (size_t)(half ? nB : nA) * C + c0);
                }
                const bool valid = (half == 0) || (j + h < tl);
                if (valid) {
                    float e, u, lu0, lu1, lu2, lu3;
                    e = __expf(-cur.x); u = 1.f + e; lu0 = __log2f(u);
                    ap0 += fast_rcp(u); sx0 += cur.x; sl0 += lu0;
                    e = __expf(-cur.y); u = 1.f + e; lu1 = __log2f(u);
                    ap1 += fast_rcp(u); sx1 += cur.y; sl1 += lu1;
                    e = __expf(-cur.z); u = 1.f + e; lu2 = __log2f(u);
                    ap2 += fast_rcp(u); sx2 += cur.z; sl2 += lu2;
                    e = __expf(-cur.w); u = 1.f + e; lu3 = __log2f(u);
                    ap3 += fast_rcp(u); sx3 += cur.w; sl3 += lu3;
                    if (poslane) {
                        float lsel = (ksub & 2) ? ((ksub & 1) ? lu3 : lu2)
                                                : ((ksub & 1) ? lu1 : lu0);
                        apos += lsel;
                    }
                }
                cur = nxt;
            }
        }

        __syncthreads();   // scatter-phase LDS fully retired before overwrite
        const int g = (wave << 1) | half;
        *reinterpret_cast<float4*>(&sP[g][c0]) = make_float4(ap0, ap1, ap2, ap3);
        *reinterpret_cast<float4*>(&sX[g][c0]) = make_float4(sx0, sx1, sx2, sx3);
        *reinterpret_cast<float4*>(&sL[g][c0]) = make_float4(sl0, sl1, sl2, sl3);
        if (poslane) sSmall[g] = apos;
        __syncthreads();

        float* mine = partial + (size_t)bid * PBS;
        if (tid < C) {                        // sum_probs col
            float s = 0.f;
#pragma unroll
            for (int g2 = 0; g2 < 8; ++g2) s += sP[g2][tid];
            mine[tid] = s;
        } else {                              // sum_logneg: -sum(x) - ln2*sum(log2(1+e))
            const int t = tid - C;
            float sx = 0.f, sl = 0.f;
#pragma unroll
            for (int g2 = 0; g2 < 8; ++g2) { sx += sX[g2][t]; sl += sL[g2][t]; }
            mine[C + t] = -sx - LN2F * sl;
        }
        if (tid == 0) {
            float s = 0.f;
#pragma unroll
            for (int g2 = 0; g2 < 8; ++g2) s += sSmall[g2];
            mine[256] = -LN2F * s;            // sum over samples of ln(p_target)
        }
    }
    grid.sync();

    // ---- phase E1: blocks 0..127 — column-k reduce + masked softmax ----
    if (bid < C) {
        const int k = bid;
        float* spcol = &sP[0][0];
        float* slcol = &sP[1][0];

        const int j  = tid >> 1;              // class row 0..127
        const int q4 = (tid & 1) * 4;
        const float* bp = partial + (size_t)(j * SPLIT + q4) * PBS;
        float aP = 0.f, aL = 0.f;
#pragma unroll
        for (int q = 0; q < 4; ++q) {
            aP += bp[q * PBS + k];
            aL += bp[q * PBS + C + k];
        }
        aP += __shfl_xor(aP, 1);              // pair (2j,2j+1) same wave
        aL += __shfl_xor(aL, 1);
        if ((tid & 1) == 0) { spcol[j] = aP; slcol[j] = aL; }
        if (tid < SPLIT) sSmall[tid] = partial[(size_t)(k * SPLIT + tid) * PBS + 256];
        __syncthreads();

        if (tid < 64) {
            const int l = tid, j0 = l, j1 = l + 64;
            const float cc0 = (float)cursor[j0];
            const float cc1 = (float)cursor[j1];
            const bool  v0 = (j0 != k) && (cc0 > 0.f);
            const bool  v1 = (j1 != k) && (cc1 > 0.f);
            const float x0 = v0 ? spcol[j0] / cc0 : -INFINITY;
            const float x1 = v1 ? spcol[j1] / cc1 : -INFINITY;

            float m = fmaxf(x0, x1);
#pragma unroll
            for (int d = 1; d < 64; d <<= 1) m = fmaxf(m, __shfl_xor(m, d));

            float w0 = v0 ? __expf(x0 - m) : 0.f;
            float w1 = v1 ? __expf(x1 - m) : 0.f;
            float den = w0 + w1;
            float num = (v0 ? w0 * (slcol[j0] / cc0) : 0.f)
                      + (v1 ? w1 * (slcol[j1] / cc1) : 0.f);
#pragma unroll
            for (int d = 1; d < 64; d <<= 1) { den += __shfl_xor(den, d); num += __shfl_xor(num, d); }

            if (l == 0) {
                float colneg = (den > 0.f) ? num / den : 0.f;
                float ck     = (float)cursor[k];
                float ps     = 0.f;
#pragma unroll
                for (int q = 0; q < SPLIT; ++q) ps += sSmall[q];
                float pk = (ck > 0.f) ? ps / ck : 0.f;
                colpart[k] = colneg + pk;     // plain store; grid.sync publishes
            }
        }
    }
    grid.sync();

    // ---- phase E2: block 0 sums the column partials ----
    if (bid == 0 && tid < 64) {
        float s = colpart[tid] + colpart[tid + 64];
#pragma unroll
        for (int d = 1; d < 64; d <<= 1) s += __shfl_xor(s, d);
        if (tid == 0) out[0] = -s;
    }
}

// ---------------------------------------------------------------------------
extern "C" void kernel_launch(void* const* d_in, const int* in_sizes, int n_in,
                              void* d_out, int out_size, void* d_ws, size_t ws_size,
                              hipStream_t stream) {
    const float* x   = (const float*)d_in[0];
    const int*   tgt = (const int*)d_in[1];
    int B = in_sizes[1];

    int*   cursor  = (int*)d_ws;                          // C ints (+pad)
    int*   perm    = cursor + 256;                        // C*CAP ints
    float* partial = (float*)(perm + C * CAP);            // NBLK*PBS floats
    float* colpart = partial + (size_t)NBLK * PBS;        // C floats
    float* outf    = (float*)d_out;

    void* args[8] = { (void*)&x, (void*)&tgt, (void*)&cursor, (void*)&perm,
                      (void*)&partial, (void*)&colpart, (void*)&outf, (void*)&B };
    hipLaunchCooperativeKernel((const void*)fused_all, dim3(NBLK), dim3(256),
                               args, 0, stream);
}

// Round 13
// 57.077 us; speedup vs baseline: 7.7324x; 7.7324x over previous
//
#include <hip/hip_runtime.h>
#include <math.h>

#define C      128
#define CAPLG  12
#define CAP    (1 << CAPLG)      // bucket capacity per class (max count ~2300 << 4096)
#define SPLIT  4                 // blocks per class in main pass (512 blocks)
#define SPB    2048              // samples per scatter block (128 blocks)
#define PBS    260               // per-block partial stride: sp[128] sln[128] pos pad
#define LN2F   0.69314718056f

__device__ __forceinline__ float fast_rcp(float x) { return __builtin_amdgcn_rcpf(x); }

// ---------------------------------------------------------------------------
// Bucketed counting-sort scatter. SPB=2048 -> 128 blocks: halves the serial
// per-class global-atomic chain (128 deep instead of 256).
__global__ __launch_bounds__(256)
void scatter_kernel(const int* __restrict__ tgt, int* __restrict__ cursor,
                    int* __restrict__ perm, int B) {
    __shared__ int lcur[C];
    __shared__ int sbase[C];
    if (threadIdx.x < C) lcur[threadIdx.x] = 0;
    __syncthreads();
    const int base = blockIdx.x * SPB;
    int myt[SPB / 256], myr[SPB / 256];
#pragma unroll
    for (int j = 0; j < SPB / 256; ++j) {
        int i = base + j * 256 + threadIdx.x;
        if (i < B) { myt[j] = tgt[i]; myr[j] = atomicAdd(&lcur[myt[j]], 1); }
        else myt[j] = -1;
    }
    __syncthreads();
    if (threadIdx.x < C) sbase[threadIdx.x] = atomicAdd(&cursor[threadIdx.x], lcur[threadIdx.x]);
    __syncthreads();
#pragma unroll
    for (int j = 0; j < SPB / 256; ++j)
        if (myt[j] >= 0)
            perm[(myt[j] << CAPLG) + sbase[myt[j]] + myr[j]] = base + j * 256 + threadIdx.x;
}

// ---------------------------------------------------------------------------
// Main pass (round-5 champion body — measured at the transcendental roofline
// ~21 us; DO NOT TOUCH the inner loop). SPLIT=4: 512 blocks, same total work.
__global__ __launch_bounds__(256)
void main_kernel(const float* __restrict__ x, const int* __restrict__ perm,
                 const int* __restrict__ cursor, float* __restrict__ partial) {
    const int k = blockIdx.x / SPLIT;
    const int p = blockIdx.x % SPLIT;
    const int n = min(cursor[k], CAP);
    const int chunk = (n + SPLIT - 1) / SPLIT;
    const int s0 = min(p * chunk, n);
    const int s1 = min(s0 + chunk, n);

    const int tid  = threadIdx.x;
    const int wave = tid >> 6;
    const int lane = tid & 63;
    const int half = lane >> 5;          // 0 => row A, 1 => row B
    const int l5   = lane & 31;
    const int c0   = l5 << 2;            // this lane's first of 4 columns
    const bool poslane = (l5 == (k >> 2));
    const int  ksub = k & 3;

    const int wlen = (s1 - s0 + 3) >> 2; // per-wave contiguous sub-range
    const int ws0  = s0 + wave * wlen;
    const int ws1  = min(ws0 + wlen, s1);

    const int* bperm = perm + (k << CAPLG);

    float ap0=0,ap1=0,ap2=0,ap3=0;       // sum p
    float sx0=0,sx1=0,sx2=0,sx3=0;       // sum x
    float sl0=0,sl1=0,sl2=0,sl3=0;       // sum log2(1+exp(-x))
    float apos = 0.f;

    for (int tbase = ws0; tbase < ws1; tbase += 64) {
        const int tl = min(64, ws1 - tbase);
        const int pv = (lane < tl) ? bperm[tbase + lane] : 0;  // one load / 64 samples
        const int h  = (tl + 1) >> 1;
        int iA = __shfl(pv, 0);
        int iB = __shfl(pv, (h < tl) ? h : 0);
        float4 cur = *reinterpret_cast<const float4*>(
                         x + (size_t)(half ? iB : iA) * C + c0);
        for (int j = 0; j < h; ++j) {
            float4 nxt = cur;
            if (j + 1 < h) {   // prefetch next pair while computing current
                int nA = __shfl(pv, j + 1);
                int nB = __shfl(pv, (j + 1 + h < tl) ? j + 1 + h : j + 1);
                nxt = *reinterpret_cast<const float4*>(
                          x + (size_t)(half ? nB : nA) * C + c0);
            }
            const bool valid = (half == 0) || (j + h < tl);
            if (valid) {
                float e, u, lu0, lu1, lu2, lu3;
                e = __expf(-cur.x); u = 1.f + e; lu0 = __log2f(u);
                ap0 += fast_rcp(u); sx0 += cur.x; sl0 += lu0;
                e = __expf(-cur.y); u = 1.f + e; lu1 = __log2f(u);
                ap1 += fast_rcp(u); sx1 += cur.y; sl1 += lu1;
                e = __expf(-cur.z); u = 1.f + e; lu2 = __log2f(u);
                ap2 += fast_rcp(u); sx2 += cur.z; sl2 += lu2;
                e = __expf(-cur.w); u = 1.f + e; lu3 = __log2f(u);
                ap3 += fast_rcp(u); sx3 += cur.w; sl3 += lu3;
                if (poslane) {   // target-column log2(1+e) (k uniform -> uniform select)
                    float lsel = (ksub & 2) ? ((ksub & 1) ? lu3 : lu2)
                                            : ((ksub & 1) ? lu1 : lu0);
                    apos += lsel;
                }
            }
            cur = nxt;
        }
    }

    // ---- cross-wave/half LDS reduce (plain float4 writes, no atomics) ----
    __shared__ __align__(16) float sP[8][C];
    __shared__ __align__(16) float sX[8][C];
    __shared__ __align__(16) float sL[8][C];
    __shared__ float sPos[8];
    const int g = (wave << 1) | half;
    *reinterpret_cast<float4*>(&sP[g][c0]) = make_float4(ap0, ap1, ap2, ap3);
    *reinterpret_cast<float4*>(&sX[g][c0]) = make_float4(sx0, sx1, sx2, sx3);
    *reinterpret_cast<float4*>(&sL[g][c0]) = make_float4(sl0, sl1, sl2, sl3);
    if (poslane) sPos[g] = apos;
    __syncthreads();

    float* mine = partial + (size_t)blockIdx.x * PBS;
    if (tid < C) {                        // sum_probs col
        float s = 0.f;
#pragma unroll
        for (int g2 = 0; g2 < 8; ++g2) s += sP[g2][tid];
        mine[tid] = s;
    } else {                              // sum_logneg col: -sum(x) - ln2*sum(log2(1+e))
        const int t = tid - C;
        float sx = 0.f, sl = 0.f;
#pragma unroll
        for (int g2 = 0; g2 < 8; ++g2) { sx += sX[g2][t]; sl += sL[g2][t]; }
        mine[C + t] = -sx - LN2F * sl;
    }
    if (tid == 0) {
        float s = 0.f;
#pragma unroll
        for (int g2 = 0; g2 < 8; ++g2) s += sPos[g2];
        mine[256] = -LN2F * s;            // sum over samples of ln(p_target)
    }
}

// ---------------------------------------------------------------------------
// Sum the SPLIT partials of each class into red (champion pattern, SPLIT=4).
__global__ __launch_bounds__(256)
void reduce2_kernel(const float* __restrict__ partial, const int* __restrict__ cursor,
                    float* __restrict__ red) {
    const int k = blockIdx.x;
    const int t = threadIdx.x;
    float s = 0.f;
#pragma unroll
    for (int p = 0; p < SPLIT; ++p)
        s += partial[(size_t)(k * SPLIT + p) * PBS + t];
    if (t < C) red[k * C + t] = s;                 // sum_probs row k
    else       red[C * C + k * C + (t - C)] = s;   // sum_logneg row k
    if (t == 0) {
        float ps = 0.f;
#pragma unroll
        for (int p = 0; p < SPLIT; ++p)
            ps += partial[(size_t)(k * SPLIT + p) * PBS + 256];
        red[2 * C * C + C + k] = ps;               // pos[k]
        red[2 * C * C + k]     = (float)cursor[k]; // cnt[k]
    }
}

// ---------------------------------------------------------------------------
// Finalize: champion fcol VERBATIM + ticketed last-block sum (isolates the
// ticket cost — the only delta vs the champion epilogue is removing fsum's
// launch; access patterns unchanged).
__global__ __launch_bounds__(64)
void finalize_col_kernel(const float* __restrict__ red, float* __restrict__ colpart,
                         int* __restrict__ ticket, float* __restrict__ out) {
    const float* sp  = red;                   // sum_probs  [C][C]
    const float* sln = red + C * C;           // sum_logneg [C][C]
    const float* cnt = red + 2 * C * C;       // [C]
    const float* pos = red + 2 * C * C + C;   // [C]

    const int k = blockIdx.x;
    const int l = threadIdx.x;
    const int j0 = l, j1 = l + 64;

    const float c0 = cnt[j0], c1 = cnt[j1];
    const bool  v0 = (j0 != k) && (c0 > 0.f);
    const bool  v1 = (j1 != k) && (c1 > 0.f);

    const float x0 = v0 ? sp[j0 * C + k] / c0 : -INFINITY;
    const float x1 = v1 ? sp[j1 * C + k] / c1 : -INFINITY;

    float m = fmaxf(x0, x1);
#pragma unroll
    for (int d = 1; d < 64; d <<= 1) m = fmaxf(m, __shfl_xor(m, d));

    float w0 = v0 ? __expf(x0 - m) : 0.f;
    float w1 = v1 ? __expf(x1 - m) : 0.f;
    float den = w0 + w1;
    float num = (v0 ? w0 * (sln[j0 * C + k] / c0) : 0.f)
              + (v1 ? w1 * (sln[j1 * C + k] / c1) : 0.f);
#pragma unroll
    for (int d = 1; d < 64; d <<= 1) { den += __shfl_xor(den, d); num += __shfl_xor(num, d); }

    int last = 0;
    if (l == 0) {
        float colneg = (den > 0.f) ? num / den : 0.f;
        float ck     = cnt[k];
        float pk     = (ck > 0.f) ? pos[k] / ck : 0.f;
        colpart[k]   = colneg + pk;
        __threadfence();                       // publish colpart before ticket
        last = (atomicAdd(ticket, 1) == C - 1);
    }
    last = __shfl(last, 0);
    if (last) {                                // last block: global sum -> out
        __threadfence();                       // acquire others' colpart
        float s = colpart[l] + colpart[l + 64];
#pragma unroll
        for (int d = 1; d < 64; d <<= 1) s += __shfl_xor(s, d);
        if (l == 0) out[0] = -s;
    }
}

// ---------------------------------------------------------------------------
extern "C" void kernel_launch(void* const* d_in, const int* in_sizes, int n_in,
                              void* d_out, int out_size, void* d_ws, size_t ws_size,
                              hipStream_t stream) {
    const float* x   = (const float*)d_in[0];
    const int*   tgt = (const int*)d_in[1];
    const int B = in_sizes[1];

    int*   cursor  = (int*)d_ws;                          // C ints
    int*   ticket  = cursor + C;                          // 1 int (zeroed with cursor)
    int*   perm    = cursor + C + 16;                     // C*CAP ints
    float* partial = (float*)(perm + C * CAP);            // C*SPLIT*PBS floats
    float* red     = partial + (size_t)(C * SPLIT) * PBS; // 2CC+2C floats
    float* colpart = red + 2 * C * C + 2 * C;             // C floats

    hipMemsetAsync(cursor, 0, (C + 16) * sizeof(int), stream);   // cursor + ticket
    scatter_kernel<<<(B + SPB - 1) / SPB, 256, 0, stream>>>(tgt, cursor, perm, B);
    main_kernel<<<C * SPLIT, 256, 0, stream>>>(x, perm, cursor, partial);
    reduce2_kernel<<<C, 256, 0, stream>>>(partial, cursor, red);
    finalize_col_kernel<<<C, 64, 0, stream>>>(red, colpart, ticket, (float*)d_out);
}